// Round 4
// baseline (405.527 us; speedup 1.0000x reference)
//
#include <hip/hip_runtime.h>
#include <hip/hip_bf16.h>

typedef __attribute__((ext_vector_type(8))) short short8;
typedef __attribute__((ext_vector_type(16))) float f32x16;
typedef unsigned short u16;
typedef unsigned int u32;

// ---------------- workspace layout (bytes) ----------------
#define OFF_XT      0u          // x NHWC bf16: 4*64*64*256 = 8388608 B ; reused as ybr (4 MB) after mdcn
#define OFF_OM      8388608u    // offsets fp32: 16384*32*4  = 2097152 B
#define OFF_Y       10485760u   // mdcn out NHWC bf16: 16384*128*2 = 4194304 B
#define OFF_Y2      14680064u   // deconv out NHWC bf16: 65536*128*2 = 16777216 B
#define OFF_BOFF    31457280u   // B_off_T  [32][2304] bf16  = 147456 B
#define OFF_BDCN    31604736u   // B_dcn_T  [128][2304] bf16 = 589824 B
#define OFF_BUP     32194560u   // B_up_T   [4][128][512] bf16 = 524288 B
#define OFF_STATS   32718848u   // stats1 sum/ss [256] + stats2 [256] f32 = 2048 B
#define OFF_BN1     32720896u   // float2[128]
#define OFF_BN2     32721920u   // float2[128]

__device__ __forceinline__ float lo2f(u32 u){ u32 v = u << 16; float f; __builtin_memcpy(&f, &v, 4); return f; }
__device__ __forceinline__ float hi2f(u32 u){ u32 v = u & 0xffff0000u; float f; __builtin_memcpy(&f, &v, 4); return f; }
__device__ __forceinline__ float b2f(u16 v){ u32 u = ((u32)v) << 16; float f; __builtin_memcpy(&f, &u, 4); return f; }
__device__ __forceinline__ u16 f2b(float f){ __hip_bfloat16 h = __float2bfloat16(f); u16 r; __builtin_memcpy(&r, &h, 2); return r; }

__device__ __forceinline__ f32x16 mfma32(short8 a, short8 b, f32x16 c){
  return __builtin_amdgcn_mfma_f32_32x32x16_bf16(a, b, c, 0, 0, 0);
}
__device__ __forceinline__ void unpk(uint4 u, float* f){
  f[0]=lo2f(u.x); f[1]=hi2f(u.x); f[2]=lo2f(u.y); f[3]=hi2f(u.y);
  f[4]=lo2f(u.z); f[5]=hi2f(u.z); f[6]=lo2f(u.w); f[7]=hi2f(u.w);
}

// ---------------- weight reorganization (f32 -> bf16) ----------------
__global__ __launch_bounds__(256) void prep_kernel(const float* __restrict__ w_off,
                                                   const float* __restrict__ w_dcn,
                                                   const float* __restrict__ w_up,
                                                   u16* __restrict__ Boff,
                                                   u16* __restrict__ Bdcn,
                                                   u16* __restrict__ Bup){
  int i = blockIdx.x * 256 + threadIdx.x;
  if (i < 32*2304){
    int o = i / 2304, kk = i % 2304, tap = kk >> 8, c = kk & 255;
    int ky = tap / 3, kx = tap - ky*3;
    u16 v = 0;
    if (o < 27) v = f2b(w_off[((o*256 + c)*3 + ky)*3 + kx]);
    Boff[i] = v;
  }
  if (i < 128*2304){
    int o = i / 2304, kk = i % 2304, tap = kk >> 8, c = kk & 255;
    int ky = tap / 3, kx = tap - ky*3;
    Bdcn[i] = f2b(w_dcn[((o*256 + c)*3 + ky)*3 + kx]);
  }
  if (i < 4*128*512){
    int pp = i / (128*512), r = i % (128*512);
    int o = r >> 9, kk = r & 511, tapd = kk >> 7, c = kk & 127;
    int py = pp >> 1, px = pp & 1, dy = tapd >> 1, dx = tapd & 1;
    Bup[i] = f2b(w_up[((c*128 + o)*4 + (3-(py+2*dy)))*4 + (3-(px+2*dx))]);
  }
}

// ---------------- x NCHW f32 -> NHWC bf16 ----------------
__global__ __launch_bounds__(256) void transpose_kernel(const float* __restrict__ x, u16* __restrict__ xt){
  __shared__ u16 Ls[64][65];
  int blk = blockIdx.x;                 // 1024 = 4b * 64h * 4cb
  int cb = blk & 3, h = (blk >> 2) & 63, b = blk >> 8;
  int t = threadIdx.x;
  int c0 = cb * 64;
  for (int i = 0; i < 16; i++){
    int idx = t + i*256;
    int c = idx >> 6, w = idx & 63;
    Ls[c][w] = f2b(x[((b*256 + c0 + c)*64 + h)*64 + w]);
  }
  __syncthreads();
  for (int i = 0; i < 16; i++){
    int idx = t + i*256;
    int w = idx >> 6, cc = idx & 63;
    xt[(((b*64 + h)*64 + w) << 8) + c0 + cc] = Ls[cc][w];
  }
}

// ---------------- stage 1: offset conv, 1 wave = 32px x 32out, K=2304 ----------------
__global__ __launch_bounds__(64) void convoff_kernel(const u16* __restrict__ xt,
                                                     const u16* __restrict__ Boff,
                                                     const float* __restrict__ b_off,
                                                     float* __restrict__ om){
  int blk = blockIdx.x;                 // 512 = 4b * 64h * 2wt
  int wt = blk & 1, h = (blk >> 1) & 63, b = blk >> 7;
  int lane = threadIdx.x;
  int m = lane & 31, kh = lane >> 5;
  int w = wt*32 + m;
  f32x16 acc = {0.f};
  const u16* Brow = Boff + m*2304 + kh*8;   // n = lane&31
  for (int s = 0; s < 144; s++){
    int tap = s >> 4, q = s & 15;
    int ky = tap / 3, kx = tap - ky*3;
    int y = h + ky - 1, xw = w + kx - 1;
    short8 a = {0,0,0,0,0,0,0,0};
    if ((u32)y < 64u && (u32)xw < 64u)
      a = *(const short8*)(xt + (((b*64 + y)*64 + xw) << 8) + q*16 + kh*8);
    short8 bb = *(const short8*)(Brow + s*16);
    acc = mfma32(a, bb, acc);
  }
  int n = lane & 31;
  if (n < 27){
    float bias = b_off[n];
    #pragma unroll
    for (int r = 0; r < 16; r++){
      int row = (r & 3) + 8*(r >> 2) + 4*kh;
      int pix = (b*64 + h)*64 + wt*32 + row;
      om[pix*32 + n] = acc[r] + bias;
    }
  }
}

// ---------------- stage 2: mdcn, 1 wave = 32px x 128out, K=2304, no LDS/barriers ----------------
__global__ __launch_bounds__(64) void mdcn_kernel(const u16* __restrict__ xt,
                                                  const float* __restrict__ om,
                                                  const u16* __restrict__ Bdcn,
                                                  const float* __restrict__ b_dcn,
                                                  u16* __restrict__ yb){
  int blk = blockIdx.x;                 // 512 = 4b * 64h * 2wt
  int wt = blk & 1, h = (blk >> 1) & 63, b = blk >> 7;
  int lane = threadIdx.x;
  int m = lane & 31, kh = lane >> 5;
  int w = wt*32 + m;
  int P = (b*64 + h)*64 + w;
  f32x16 acc[4];
  #pragma unroll
  for (int a4 = 0; a4 < 4; a4++) acc[a4] = (f32x16){0.f};

  for (int k = 0; k < 9; k++){
    int ky = k / 3, kx = k - ky*3;
    float dy = om[P*32 + 2*k];
    float dx = om[P*32 + 2*k + 1];
    float mk = 1.f / (1.f + __expf(-om[P*32 + 18 + k]));
    float ysf = (float)(h - 1 + ky) + dy;
    float xsf = (float)(w - 1 + kx) + dx;
    float y0f = floorf(ysf), x0f = floorf(xsf);
    float ly = ysf - y0f, lx = xsf - x0f;
    int y0 = (int)y0f, x0i = (int)x0f;
    float w00 = (1.f-ly)*(1.f-lx)*mk, w01 = (1.f-ly)*lx*mk;
    float w10 = ly*(1.f-lx)*mk,       w11 = ly*lx*mk;
    bool ok00 = ((u32)y0 < 64u)     && ((u32)x0i < 64u);
    bool ok01 = ((u32)y0 < 64u)     && ((u32)(x0i+1) < 64u);
    bool ok10 = ((u32)(y0+1) < 64u) && ((u32)x0i < 64u);
    bool ok11 = ((u32)(y0+1) < 64u) && ((u32)(x0i+1) < 64u);
    int a00 = ((b*64 + y0)*64 + x0i) << 8;
    int a01 = a00 + 256, a10 = a00 + (64 << 8), a11 = a10 + 256;

    for (int q = 0; q < 16; q++){
      int c = q*16 + kh*8;
      uint4 z = make_uint4(0,0,0,0);
      uint4 u00 = ok00 ? *(const uint4*)(xt + a00 + c) : z;
      uint4 u01 = ok01 ? *(const uint4*)(xt + a01 + c) : z;
      uint4 u10 = ok10 ? *(const uint4*)(xt + a10 + c) : z;
      uint4 u11 = ok11 ? *(const uint4*)(xt + a11 + c) : z;
      float f00[8], f01[8], f10[8], f11[8];
      unpk(u00, f00); unpk(u01, f01); unpk(u10, f10); unpk(u11, f11);
      short8 av;
      #pragma unroll
      for (int j = 0; j < 8; j++){
        float t0 = w00*f00[j] + w01*f01[j];
        float t1 = w10*f10[j] + w11*f11[j];
        av[j] = (short)f2b(t0 + t1);
      }
      int ks = k*256 + q*16 + kh*8;
      #pragma unroll
      for (int a4 = 0; a4 < 4; a4++){
        short8 bb = *(const short8*)(Bdcn + (a4*32 + m)*2304 + ks);
        acc[a4] = mfma32(av, bb, acc[a4]);
      }
    }
  }
  #pragma unroll
  for (int a4 = 0; a4 < 4; a4++){
    int ch = a4*32 + m;
    float bias = b_dcn[ch];
    #pragma unroll
    for (int r = 0; r < 16; r++){
      int row = (r & 3) + 8*(r >> 2) + 4*kh;
      int pix = (b*64 + h)*64 + wt*32 + row;
      yb[pix*128 + ch] = f2b(acc[a4][r] + bias);
    }
  }
}

// ---------------- BN stats: per-channel sum/sumsq over NHWC bf16 ----------------
__global__ __launch_bounds__(256) void bnstats_kernel(const u16* __restrict__ src,
                                                      float* __restrict__ st, int npix){
  __shared__ float red[256];
  int t = threadIdx.x;
  int ch = t & 127, half = t >> 7;
  float s = 0.f, ss = 0.f;
  for (int p = blockIdx.x*2 + half; p < npix; p += gridDim.x*2){
    float v = b2f(src[p*128 + ch]);
    s += v; ss += v*v;
  }
  red[t] = s; __syncthreads();
  if (t < 128) atomicAdd(&st[t], red[t] + red[t+128]);
  __syncthreads();
  red[t] = ss; __syncthreads();
  if (t < 128) atomicAdd(&st[128 + t], red[t] + red[t+128]);
}

// ---------------- BN finalize ----------------
__global__ __launch_bounds__(128) void bnfin_kernel(const float* __restrict__ stats,
                                                    const float* __restrict__ gamma,
                                                    const float* __restrict__ beta,
                                                    float2* __restrict__ bn,
                                                    float invN){
  int o = threadIdx.x;
  float mean = stats[o] * invN;
  float var  = stats[128 + o] * invN - mean*mean;
  float inv  = rsqrtf(var + 1e-5f);
  float sc   = gamma[o] * inv;
  bn[o] = make_float2(sc, beta[o] - mean * sc);
}

// ---------------- BN1 + ReLU elementwise: yb -> ybr ----------------
__global__ __launch_bounds__(256) void bnapply_kernel(const u16* __restrict__ yb,
                                                      const float2* __restrict__ bn1,
                                                      u16* __restrict__ ybr){
  int gid = blockIdx.x*256 + threadIdx.x;     // 1024 blocks: 262144 threads x 8 ch
  int pix = gid >> 4, cg = (gid & 15) * 8;
  uint4 u = *(const uint4*)(yb + pix*128 + cg);
  float f[8]; unpk(u, f);
  u16 p[8];
  #pragma unroll
  for (int e = 0; e < 8; e++){
    float2 sc = bn1[cg + e];
    p[e] = f2b(fmaxf(0.f, fmaf(sc.x, f[e], sc.y)));
  }
  uint4 r;
  r.x = (u32)p[0] | ((u32)p[1] << 16);
  r.y = (u32)p[2] | ((u32)p[3] << 16);
  r.z = (u32)p[4] | ((u32)p[5] << 16);
  r.w = (u32)p[6] | ((u32)p[7] << 16);
  *(uint4*)(ybr + pix*128 + cg) = r;
}

// ---------------- stage 4: deconv, 1 wave = 32px x 128out, K=512 ----------------
__global__ __launch_bounds__(64) void deconv_kernel(const u16* __restrict__ ybr,
                                                    const u16* __restrict__ Bup,
                                                    u16* __restrict__ y2){
  int blk = blockIdx.x;                 // 2048 = 4b * 128yy * 2parx * 2xtl
  int xtl = blk & 1, parx = (blk >> 1) & 1, yy = (blk >> 2) & 127, b = blk >> 9;
  int pary = yy & 1, pp = pary*2 + parx;
  int hs = (yy - 2 + pary) / 2;         // exact, may be -1
  int lane = threadIdx.x;
  int m = lane & 31, kh = lane >> 5;
  int j = xtl*32 + m;
  f32x16 acc[4];
  #pragma unroll
  for (int a4 = 0; a4 < 4; a4++) acc[a4] = (f32x16){0.f};

  for (int s = 0; s < 32; s++){
    int tapd = s >> 3, q = s & 7;
    int dyy = tapd >> 1, dxx = tapd & 1;
    int hh = hs + dyy, ww = j - 1 + parx + dxx;
    int c = q*16 + kh*8;
    short8 a = {0,0,0,0,0,0,0,0};
    if ((u32)hh < 64u && (u32)ww < 64u)
      a = *(const short8*)(ybr + (((b*64 + hh)*64 + ww) << 7) + c);
    #pragma unroll
    for (int a4 = 0; a4 < 4; a4++){
      short8 bb = *(const short8*)(Bup + (pp*128 + a4*32 + m)*512 + tapd*128 + c);
      acc[a4] = mfma32(a, bb, acc[a4]);
    }
  }
  #pragma unroll
  for (int a4 = 0; a4 < 4; a4++){
    int ch = a4*32 + m;
    #pragma unroll
    for (int r = 0; r < 16; r++){
      int row = (r & 3) + 8*(r >> 2) + 4*kh;
      int jj = xtl*32 + row;
      int xx = parx + 2*jj;
      y2[(((b*128 + yy)*128 + xx) << 7) + ch] = f2b(acc[a4][r]);
    }
  }
}

// ---------------- stage 5: BN2 + ReLU + NHWC->NCHW, f32 out ----------------
__global__ __launch_bounds__(256) void final_kernel(const u16* __restrict__ y2,
                                                    const float2* __restrict__ bn2,
                                                    float* __restrict__ outp){
  __shared__ u16 Ls[128*132];
  __shared__ float2 BNs[128];
  int blk = blockIdx.x;                 // 512 = 4b * 128y
  int yy = blk & 127, b = blk >> 7;
  int t = threadIdx.x;
  if (t < 128) BNs[t] = bn2[t];
  __syncthreads();
  for (int i = 0; i < 8; i++){
    int x = i*16 + (t >> 4);
    int og = (t & 15) * 8;
    uint4 u = *(const uint4*)(y2 + (((b*128 + yy)*128 + x) << 7) + og);
    float f[8]; unpk(u, f);
    for (int e = 0; e < 8; e++){
      float2 sc = BNs[og + e];
      Ls[(og + e)*132 + x] = f2b(fmaxf(0.f, fmaf(sc.x, f[e], sc.y)));
    }
  }
  __syncthreads();
  for (int i = 0; i < 16; i++){
    int idx = i*256 + t;
    int o = idx >> 5, xg = (idx & 31) * 4;
    float4 v;
    v.x = b2f(Ls[o*132 + xg + 0]);
    v.y = b2f(Ls[o*132 + xg + 1]);
    v.z = b2f(Ls[o*132 + xg + 2]);
    v.w = b2f(Ls[o*132 + xg + 3]);
    *(float4*)(outp + (((b*128 + o)*128 + yy) << 7) + xg) = v;
  }
}

extern "C" void kernel_launch(void* const* d_in, const int* in_sizes, int n_in,
                              void* d_out, int out_size, void* d_ws, size_t ws_size,
                              hipStream_t stream) {
  const float* x      = (const float*)d_in[0];
  const float* w_off  = (const float*)d_in[1];
  const float* b_off  = (const float*)d_in[2];
  const float* w_dcn  = (const float*)d_in[3];
  const float* b_dcn  = (const float*)d_in[4];
  const float* gamma1 = (const float*)d_in[5];
  const float* beta1  = (const float*)d_in[6];
  const float* w_up   = (const float*)d_in[7];
  const float* gamma2 = (const float*)d_in[8];
  const float* beta2  = (const float*)d_in[9];

  char* ws = (char*)d_ws;
  u16*   xt    = (u16*)(ws + OFF_XT);
  u16*   ybr   = (u16*)(ws + OFF_XT);     // reuses xt space (xt dead after mdcn)
  float* om    = (float*)(ws + OFF_OM);
  u16*   yb    = (u16*)(ws + OFF_Y);
  u16*   y2    = (u16*)(ws + OFF_Y2);
  u16*   Boff  = (u16*)(ws + OFF_BOFF);
  u16*   Bdcn  = (u16*)(ws + OFF_BDCN);
  u16*   Bup   = (u16*)(ws + OFF_BUP);
  float* stats = (float*)(ws + OFF_STATS);
  float2* bn1  = (float2*)(ws + OFF_BN1);
  float2* bn2  = (float2*)(ws + OFF_BN2);

  hipMemsetAsync(stats, 0, 2048, stream);
  prep_kernel<<<1152, 256, 0, stream>>>(w_off, w_dcn, w_up, Boff, Bdcn, Bup);
  transpose_kernel<<<1024, 256, 0, stream>>>(x, xt);
  convoff_kernel<<<512, 64, 0, stream>>>(xt, Boff, b_off, om);
  mdcn_kernel<<<512, 64, 0, stream>>>(xt, om, Bdcn, b_dcn, yb);
  bnstats_kernel<<<256, 256, 0, stream>>>(yb, stats, 16384);
  bnfin_kernel<<<1, 128, 0, stream>>>(stats, gamma1, beta1, bn1, 1.f/16384.f);
  bnapply_kernel<<<1024, 256, 0, stream>>>(yb, bn1, ybr);
  deconv_kernel<<<2048, 64, 0, stream>>>(ybr, Bup, y2);
  bnstats_kernel<<<512, 256, 0, stream>>>(y2, stats + 256, 65536);
  bnfin_kernel<<<1, 128, 0, stream>>>(stats + 256, gamma2, beta2, bn2, 1.f/65536.f);
  final_kernel<<<512, 256, 0, stream>>>(y2, bn2, (float*)d_out);
}

// Round 5
// 384.441 us; speedup vs baseline: 1.0548x; 1.0548x over previous
//
#include <hip/hip_runtime.h>
#include <hip/hip_bf16.h>

typedef __attribute__((ext_vector_type(8))) short short8;
typedef __attribute__((ext_vector_type(16))) float f32x16;
typedef unsigned short u16;
typedef unsigned int u32;

// ---------------- workspace layout (bytes) ----------------
#define OFF_XT      0u          // x NHWC bf16: 4*64*64*256 = 8388608 B ; reused as ybr after mdcn
#define OFF_OM      8388608u    // offsets fp32: 16384*32*4  = 2097152 B
#define OFF_Y       10485760u   // mdcn out NHWC bf16: 16384*128*2 = 4194304 B
#define OFF_Y2      14680064u   // deconv out NHWC bf16: 65536*128*2 = 16777216 B
#define OFF_BOFF    31457280u   // B_off_T  [32][2304] bf16  = 147456 B
#define OFF_BDCN    31604736u   // B_dcn_T  [128][2304] bf16 = 589824 B
#define OFF_BUP     32194560u   // B_up_T   [4][128][512] bf16 = 524288 B
#define OFF_STATS   32718848u   // stats1 sum/ss [256] + stats2 [256] f32 = 2048 B
#define OFF_BN1     32720896u   // float2[128]
#define OFF_BN2     32721920u   // float2[128]

__device__ __forceinline__ float lo2f(u32 u){ u32 v = u << 16; float f; __builtin_memcpy(&f, &v, 4); return f; }
__device__ __forceinline__ float hi2f(u32 u){ u32 v = u & 0xffff0000u; float f; __builtin_memcpy(&f, &v, 4); return f; }
__device__ __forceinline__ float b2f(u16 v){ u32 u = ((u32)v) << 16; float f; __builtin_memcpy(&f, &u, 4); return f; }
__device__ __forceinline__ u16 f2b(float f){ __hip_bfloat16 h = __float2bfloat16(f); u16 r; __builtin_memcpy(&r, &h, 2); return r; }

__device__ __forceinline__ f32x16 mfma32(short8 a, short8 b, f32x16 c){
  return __builtin_amdgcn_mfma_f32_32x32x16_bf16(a, b, c, 0, 0, 0);
}
__device__ __forceinline__ void unpk(uint4 u, float* f){
  f[0]=lo2f(u.x); f[1]=hi2f(u.x); f[2]=lo2f(u.y); f[3]=hi2f(u.y);
  f[4]=lo2f(u.z); f[5]=hi2f(u.z); f[6]=lo2f(u.w); f[7]=hi2f(u.w);
}

// ---------------- weight reorganization (f32 -> bf16) ----------------
__global__ __launch_bounds__(256) void prep_kernel(const float* __restrict__ w_off,
                                                   const float* __restrict__ w_dcn,
                                                   const float* __restrict__ w_up,
                                                   u16* __restrict__ Boff,
                                                   u16* __restrict__ Bdcn,
                                                   u16* __restrict__ Bup){
  int i = blockIdx.x * 256 + threadIdx.x;
  if (i < 32*2304){
    int o = i / 2304, kk = i % 2304, tap = kk >> 8, c = kk & 255;
    int ky = tap / 3, kx = tap - ky*3;
    u16 v = 0;
    if (o < 27) v = f2b(w_off[((o*256 + c)*3 + ky)*3 + kx]);
    Boff[i] = v;
  }
  if (i < 128*2304){
    int o = i / 2304, kk = i % 2304, tap = kk >> 8, c = kk & 255;
    int ky = tap / 3, kx = tap - ky*3;
    Bdcn[i] = f2b(w_dcn[((o*256 + c)*3 + ky)*3 + kx]);
  }
  if (i < 4*128*512){
    int pp = i / (128*512), r = i % (128*512);
    int o = r >> 9, kk = r & 511, tapd = kk >> 7, c = kk & 127;
    int py = pp >> 1, px = pp & 1, dy = tapd >> 1, dx = tapd & 1;
    Bup[i] = f2b(w_up[((c*128 + o)*4 + (3-(py+2*dy)))*4 + (3-(px+2*dx))]);
  }
}

// ---------------- x NCHW f32 -> NHWC bf16 ----------------
__global__ __launch_bounds__(256) void transpose_kernel(const float* __restrict__ x, u16* __restrict__ xt){
  __shared__ u16 Ls[64][65];
  int blk = blockIdx.x;                 // 1024 = 4b * 64h * 4cb
  int cb = blk & 3, h = (blk >> 2) & 63, b = blk >> 8;
  int t = threadIdx.x;
  int c0 = cb * 64;
  for (int i = 0; i < 16; i++){
    int idx = t + i*256;
    int c = idx >> 6, w = idx & 63;
    Ls[c][w] = f2b(x[((b*256 + c0 + c)*64 + h)*64 + w]);
  }
  __syncthreads();
  for (int i = 0; i < 16; i++){
    int idx = t + i*256;
    int w = idx >> 6, cc = idx & 63;
    xt[(((b*64 + h)*64 + w) << 8) + c0 + cc] = Ls[cc][w];
  }
}

// ---------------- stage 1: offset conv; 4 waves K-split, 1 barrier ----------------
__global__ __launch_bounds__(256) void convoff_kernel(const u16* __restrict__ xt,
                                                      const u16* __restrict__ Boff,
                                                      const float* __restrict__ b_off,
                                                      float* __restrict__ om){
  __shared__ float Ys[3][64][17];
  int blk = blockIdx.x;                 // 512 = 4b * 64h * 2wt
  int wt = blk & 1, h = (blk >> 1) & 63, b = blk >> 7;
  int t = threadIdx.x;
  int wv = t >> 6, lane = t & 63;
  int m = lane & 31, kh = lane >> 5;
  int w = wt*32 + m;
  int cw = wv * 64;
  f32x16 acc = {0.f};
  const u16* Brow = Boff + m*2304 + cw + kh*8;
  #pragma unroll
  for (int k = 0; k < 9; k++){
    int ky = k / 3, kx = k - ky*3;
    int y = h + ky - 1, xw = w + kx - 1;
    bool ok = ((u32)y < 64u) && ((u32)xw < 64u);
    int base = (((b*64 + y)*64 + xw) << 8) + cw + kh*8;
    #pragma unroll
    for (int q = 0; q < 4; q++){
      short8 a = {0,0,0,0,0,0,0,0};
      if (ok) a = *(const short8*)(xt + base + q*16);
      short8 bb = *(const short8*)(Brow + k*256 + q*16);
      acc = mfma32(a, bb, acc);
    }
  }
  if (wv > 0){
    #pragma unroll
    for (int r = 0; r < 16; r++) Ys[wv-1][lane][r] = acc[r];
  }
  __syncthreads();
  if (wv == 0){
    int n = m;
    float bias = (n < 27) ? b_off[n] : 0.f;
    #pragma unroll
    for (int r = 0; r < 16; r++){
      float s = acc[r] + Ys[0][lane][r] + Ys[1][lane][r] + Ys[2][lane][r];
      int row = (r & 3) + 8*(r >> 2) + 4*kh;
      int pix = (b*64 + h)*64 + wt*32 + row;
      om[pix*32 + n] = s + bias;
    }
  }
}

// ---------------- stage 2: mdcn; 4 waves K-split (64ch each), 1 barrier ----------------
__global__ __launch_bounds__(256) void mdcn_kernel(const u16* __restrict__ xt,
                                                   const float* __restrict__ om,
                                                   const u16* __restrict__ Bdcn,
                                                   const float* __restrict__ b_dcn,
                                                   u16* __restrict__ yb){
  __shared__ float Ys[3][64][65];
  int blk = blockIdx.x;                 // 512 = 4b * 64h * 2wt
  int wt = blk & 1, h = (blk >> 1) & 63, b = blk >> 7;
  int t = threadIdx.x;
  int wv = t >> 6, lane = t & 63;
  int m = lane & 31, kh = lane >> 5;
  int w = wt*32 + m;
  int P0 = (b*64 + h)*64 + wt*32;
  int P = P0 + m;
  int cw = wv * 64;
  f32x16 acc[4];
  #pragma unroll
  for (int a4 = 0; a4 < 4; a4++) acc[a4] = (f32x16){0.f};

  for (int k = 0; k < 9; k++){
    int ky = k / 3, kx = k - ky*3;
    float dy = om[P*32 + 2*k];
    float dx = om[P*32 + 2*k + 1];
    float mk = 1.f / (1.f + __expf(-om[P*32 + 18 + k]));
    float ysf = (float)(h - 1 + ky) + dy;
    float xsf = (float)(w - 1 + kx) + dx;
    float y0f = floorf(ysf), x0f = floorf(xsf);
    float ly = ysf - y0f, lx = xsf - x0f;
    int y0 = (int)y0f, x0i = (int)x0f;
    float w00 = (1.f-ly)*(1.f-lx)*mk, w01 = (1.f-ly)*lx*mk;
    float w10 = ly*(1.f-lx)*mk,       w11 = ly*lx*mk;
    bool ok00 = ((u32)y0 < 64u)     && ((u32)x0i < 64u);
    bool ok01 = ((u32)y0 < 64u)     && ((u32)(x0i+1) < 64u);
    bool ok10 = ((u32)(y0+1) < 64u) && ((u32)x0i < 64u);
    bool ok11 = ((u32)(y0+1) < 64u) && ((u32)(x0i+1) < 64u);
    int a00 = (((b*64 + y0)*64 + x0i) << 8) + cw + kh*8;
    int a01 = a00 + 256, a10 = a00 + (64 << 8), a11 = a10 + 256;

    #pragma unroll
    for (int q = 0; q < 4; q++){
      int c = q*16;
      uint4 z = make_uint4(0,0,0,0);
      uint4 u00 = ok00 ? *(const uint4*)(xt + a00 + c) : z;
      uint4 u01 = ok01 ? *(const uint4*)(xt + a01 + c) : z;
      uint4 u10 = ok10 ? *(const uint4*)(xt + a10 + c) : z;
      uint4 u11 = ok11 ? *(const uint4*)(xt + a11 + c) : z;
      float f00[8], f01[8], f10[8], f11[8];
      unpk(u00, f00); unpk(u01, f01); unpk(u10, f10); unpk(u11, f11);
      short8 av;
      #pragma unroll
      for (int j = 0; j < 8; j++){
        float t0 = w00*f00[j] + w01*f01[j];
        float t1 = w10*f10[j] + w11*f11[j];
        av[j] = (short)f2b(t0 + t1);
      }
      int ks = k*256 + cw + q*16 + kh*8;
      #pragma unroll
      for (int a4 = 0; a4 < 4; a4++){
        short8 bb = *(const short8*)(Bdcn + (a4*32 + m)*2304 + ks);
        acc[a4] = mfma32(av, bb, acc[a4]);
      }
    }
  }
  if (wv > 0){
    #pragma unroll
    for (int a4 = 0; a4 < 4; a4++)
      #pragma unroll
      for (int r = 0; r < 16; r++)
        Ys[wv-1][lane][a4*16 + r] = acc[a4][r];
  }
  __syncthreads();
  if (wv == 0){
    #pragma unroll
    for (int a4 = 0; a4 < 4; a4++){
      int ch = a4*32 + m;
      float bias = b_dcn[ch];
      #pragma unroll
      for (int r = 0; r < 16; r++){
        int i = a4*16 + r;
        float s = acc[a4][r] + Ys[0][lane][i] + Ys[1][lane][i] + Ys[2][lane][i];
        int row = (r & 3) + 8*(r >> 2) + 4*kh;
        yb[(P0 + row)*128 + ch] = f2b(s + bias);
      }
    }
  }
}

// ---------------- BN stats: per-channel sum/sumsq over NHWC bf16 ----------------
__global__ __launch_bounds__(256) void bnstats_kernel(const u16* __restrict__ src,
                                                      float* __restrict__ st, int npix){
  __shared__ float red[256];
  int t = threadIdx.x;
  int ch = t & 127, half = t >> 7;
  float s = 0.f, ss = 0.f;
  for (int p = blockIdx.x*2 + half; p < npix; p += gridDim.x*2){
    float v = b2f(src[p*128 + ch]);
    s += v; ss += v*v;
  }
  red[t] = s; __syncthreads();
  if (t < 128) atomicAdd(&st[t], red[t] + red[t+128]);
  __syncthreads();
  red[t] = ss; __syncthreads();
  if (t < 128) atomicAdd(&st[128 + t], red[t] + red[t+128]);
}

// ---------------- BN finalize ----------------
__global__ __launch_bounds__(128) void bnfin_kernel(const float* __restrict__ stats,
                                                    const float* __restrict__ gamma,
                                                    const float* __restrict__ beta,
                                                    float2* __restrict__ bn,
                                                    float invN){
  int o = threadIdx.x;
  float mean = stats[o] * invN;
  float var  = stats[128 + o] * invN - mean*mean;
  float inv  = rsqrtf(var + 1e-5f);
  float sc   = gamma[o] * inv;
  bn[o] = make_float2(sc, beta[o] - mean * sc);
}

// ---------------- BN1 + ReLU elementwise: yb -> ybr ----------------
__global__ __launch_bounds__(256) void bnapply_kernel(const u16* __restrict__ yb,
                                                      const float2* __restrict__ bn1,
                                                      u16* __restrict__ ybr){
  int gid = blockIdx.x*256 + threadIdx.x;
  int pix = gid >> 4, cg = (gid & 15) * 8;
  uint4 u = *(const uint4*)(yb + pix*128 + cg);
  float f[8]; unpk(u, f);
  u16 p[8];
  #pragma unroll
  for (int e = 0; e < 8; e++){
    float2 sc = bn1[cg + e];
    p[e] = f2b(fmaxf(0.f, fmaf(sc.x, f[e], sc.y)));
  }
  uint4 r;
  r.x = (u32)p[0] | ((u32)p[1] << 16);
  r.y = (u32)p[2] | ((u32)p[3] << 16);
  r.z = (u32)p[4] | ((u32)p[5] << 16);
  r.w = (u32)p[6] | ((u32)p[7] << 16);
  *(uint4*)(ybr + pix*128 + cg) = r;
}

// ---------------- stage 4: deconv, 1 wave = 32px x 128out, K=512 ----------------
__global__ __launch_bounds__(64) void deconv_kernel(const u16* __restrict__ ybr,
                                                    const u16* __restrict__ Bup,
                                                    u16* __restrict__ y2){
  int blk = blockIdx.x;                 // 2048 = 4b * 128yy * 2parx * 2xtl
  int xtl = blk & 1, parx = (blk >> 1) & 1, yy = (blk >> 2) & 127, b = blk >> 9;
  int pary = yy & 1, pp = pary*2 + parx;
  int hs = (yy - 2 + pary) / 2;         // exact, may be -1
  int lane = threadIdx.x;
  int m = lane & 31, kh = lane >> 5;
  int j = xtl*32 + m;
  f32x16 acc[4];
  #pragma unroll
  for (int a4 = 0; a4 < 4; a4++) acc[a4] = (f32x16){0.f};

  for (int s = 0; s < 32; s++){
    int tapd = s >> 3, q = s & 7;
    int dyy = tapd >> 1, dxx = tapd & 1;
    int hh = hs + dyy, ww = j - 1 + parx + dxx;
    int c = q*16 + kh*8;
    short8 a = {0,0,0,0,0,0,0,0};
    if ((u32)hh < 64u && (u32)ww < 64u)
      a = *(const short8*)(ybr + (((b*64 + hh)*64 + ww) << 7) + c);
    #pragma unroll
    for (int a4 = 0; a4 < 4; a4++){
      short8 bb = *(const short8*)(Bup + (pp*128 + a4*32 + m)*512 + tapd*128 + c);
      acc[a4] = mfma32(a, bb, acc[a4]);
    }
  }
  #pragma unroll
  for (int a4 = 0; a4 < 4; a4++){
    int ch = a4*32 + m;
    #pragma unroll
    for (int r = 0; r < 16; r++){
      int row = (r & 3) + 8*(r >> 2) + 4*kh;
      int jj = xtl*32 + row;
      int xx = parx + 2*jj;
      y2[(((b*128 + yy)*128 + xx) << 7) + ch] = f2b(acc[a4][r]);
    }
  }
}

// ---------------- stage 5: BN2 + ReLU + NHWC->NCHW, f32 out ----------------
__global__ __launch_bounds__(256) void final_kernel(const u16* __restrict__ y2,
                                                    const float2* __restrict__ bn2,
                                                    float* __restrict__ outp){
  __shared__ u16 Ls[128*132];
  __shared__ float2 BNs[128];
  int blk = blockIdx.x;                 // 512 = 4b * 128y
  int yy = blk & 127, b = blk >> 7;
  int t = threadIdx.x;
  if (t < 128) BNs[t] = bn2[t];
  __syncthreads();
  for (int i = 0; i < 8; i++){
    int x = i*16 + (t >> 4);
    int og = (t & 15) * 8;
    uint4 u = *(const uint4*)(y2 + (((b*128 + yy)*128 + x) << 7) + og);
    float f[8]; unpk(u, f);
    for (int e = 0; e < 8; e++){
      float2 sc = BNs[og + e];
      Ls[(og + e)*132 + x] = f2b(fmaxf(0.f, fmaf(sc.x, f[e], sc.y)));
    }
  }
  __syncthreads();
  for (int i = 0; i < 16; i++){
    int idx = i*256 + t;
    int o = idx >> 5, xg = (idx & 31) * 4;
    float4 v;
    v.x = b2f(Ls[o*132 + xg + 0]);
    v.y = b2f(Ls[o*132 + xg + 1]);
    v.z = b2f(Ls[o*132 + xg + 2]);
    v.w = b2f(Ls[o*132 + xg + 3]);
    *(float4*)(outp + (((b*128 + o)*128 + yy) << 7) + xg) = v;
  }
}

extern "C" void kernel_launch(void* const* d_in, const int* in_sizes, int n_in,
                              void* d_out, int out_size, void* d_ws, size_t ws_size,
                              hipStream_t stream) {
  const float* x      = (const float*)d_in[0];
  const float* w_off  = (const float*)d_in[1];
  const float* b_off  = (const float*)d_in[2];
  const float* w_dcn  = (const float*)d_in[3];
  const float* b_dcn  = (const float*)d_in[4];
  const float* gamma1 = (const float*)d_in[5];
  const float* beta1  = (const float*)d_in[6];
  const float* w_up   = (const float*)d_in[7];
  const float* gamma2 = (const float*)d_in[8];
  const float* beta2  = (const float*)d_in[9];

  char* ws = (char*)d_ws;
  u16*   xt    = (u16*)(ws + OFF_XT);
  u16*   ybr   = (u16*)(ws + OFF_XT);     // reuses xt space (xt dead after mdcn)
  float* om    = (float*)(ws + OFF_OM);
  u16*   yb    = (u16*)(ws + OFF_Y);
  u16*   y2    = (u16*)(ws + OFF_Y2);
  u16*   Boff  = (u16*)(ws + OFF_BOFF);
  u16*   Bdcn  = (u16*)(ws + OFF_BDCN);
  u16*   Bup   = (u16*)(ws + OFF_BUP);
  float* stats = (float*)(ws + OFF_STATS);
  float2* bn1  = (float2*)(ws + OFF_BN1);
  float2* bn2  = (float2*)(ws + OFF_BN2);

  hipMemsetAsync(stats, 0, 2048, stream);
  prep_kernel<<<1152, 256, 0, stream>>>(w_off, w_dcn, w_up, Boff, Bdcn, Bup);
  transpose_kernel<<<1024, 256, 0, stream>>>(x, xt);
  convoff_kernel<<<512, 256, 0, stream>>>(xt, Boff, b_off, om);
  mdcn_kernel<<<512, 256, 0, stream>>>(xt, om, Bdcn, b_dcn, yb);
  bnstats_kernel<<<256, 256, 0, stream>>>(yb, stats, 16384);
  bnfin_kernel<<<1, 128, 0, stream>>>(stats, gamma1, beta1, bn1, 1.f/16384.f);
  bnapply_kernel<<<1024, 256, 0, stream>>>(yb, bn1, ybr);
  deconv_kernel<<<2048, 64, 0, stream>>>(ybr, Bup, y2);
  bnstats_kernel<<<512, 256, 0, stream>>>(y2, stats + 256, 65536);
  bnfin_kernel<<<1, 128, 0, stream>>>(stats + 256, gamma2, beta2, bn2, 1.f/65536.f);
  final_kernel<<<512, 256, 0, stream>>>(y2, bn2, (float*)d_out);
}

// Round 6
// 300.273 us; speedup vs baseline: 1.3505x; 1.2803x over previous
//
#include <hip/hip_runtime.h>
#include <hip/hip_bf16.h>

typedef __attribute__((ext_vector_type(8))) short short8;
typedef __attribute__((ext_vector_type(16))) float f32x16;
typedef unsigned short u16;
typedef unsigned int u32;

// ---------------- workspace layout (bytes) ----------------
#define OFF_XT      0u          // x NHWC bf16: 4*64*64*256 = 8388608 B
#define OFF_OM      8388608u    // offsets fp32: 16384*32*4  = 2097152 B
#define OFF_Y       10485760u   // mdcn out NHWC bf16: 16384*128*2 = 4194304 B
#define OFF_Y2      14680064u   // deconv out NHWC bf16: 65536*128*2 = 16777216 B
#define OFF_BOFF    31457280u   // Boff' [144][2][32][8] bf16 = 147456 B
#define OFF_BDCN    31604736u   // Bdcn' [144][4][2][32][8] bf16 = 589824 B
#define OFF_BUP     32194560u   // Bup'  [4][32][4][2][32][8] bf16 = 524288 B
#define OFF_STATS   32718848u   // stats1 sum/ss [256] + stats2 [256] f32 = 2048 B
#define OFF_BN1     32720896u   // float2[128]
#define OFF_BN2     32721920u   // float2[128]

__device__ __forceinline__ float lo2f(u32 u){ u32 v = u << 16; float f; __builtin_memcpy(&f, &v, 4); return f; }
__device__ __forceinline__ float hi2f(u32 u){ u32 v = u & 0xffff0000u; float f; __builtin_memcpy(&f, &v, 4); return f; }
__device__ __forceinline__ float b2f(u16 v){ u32 u = ((u32)v) << 16; float f; __builtin_memcpy(&f, &u, 4); return f; }
__device__ __forceinline__ u16 f2b(float f){ __hip_bfloat16 h = __float2bfloat16(f); u16 r; __builtin_memcpy(&r, &h, 2); return r; }

__device__ __forceinline__ f32x16 mfma32(short8 a, short8 b, f32x16 c){
  return __builtin_amdgcn_mfma_f32_32x32x16_bf16(a, b, c, 0, 0, 0);
}
__device__ __forceinline__ void unpk(uint4 u, float* f){
  f[0]=lo2f(u.x); f[1]=hi2f(u.x); f[2]=lo2f(u.y); f[3]=hi2f(u.y);
  f[4]=lo2f(u.z); f[5]=hi2f(u.z); f[6]=lo2f(u.w); f[7]=hi2f(u.w);
}
__device__ __forceinline__ uint4 pk8(const float* f){
  uint4 r;
  r.x = (u32)f2b(f[0]) | ((u32)f2b(f[1]) << 16);
  r.y = (u32)f2b(f[2]) | ((u32)f2b(f[3]) << 16);
  r.z = (u32)f2b(f[4]) | ((u32)f2b(f[5]) << 16);
  r.w = (u32)f2b(f[6]) | ((u32)f2b(f[7]) << 16);
  return r;
}

// ---------------- weight reorg into MFMA-fragment layouts (f32 -> bf16) ----------------
// Boff'[kc][kh][n][j]   : k=kc*16+kh*8+j, tap=k>>8, c=k&255
// Bdcn'[kc][a4][kh][n][j]: o=a4*32+n
// Bup' [pp][kc][a4][kh][n][j]: k=kc*16+kh*8+j (K=512), tapd=k>>7, c=k&127
__global__ __launch_bounds__(256) void prep_kernel(const float* __restrict__ w_off,
                                                   const float* __restrict__ w_dcn,
                                                   const float* __restrict__ w_up,
                                                   u16* __restrict__ Boff,
                                                   u16* __restrict__ Bdcn,
                                                   u16* __restrict__ Bup){
  int i = blockIdx.x * 256 + threadIdx.x;
  if (i < 144*2*32*8){
    int j = i & 7, n = (i >> 3) & 31, kh = (i >> 8) & 1, kc = i >> 9;
    int k = kc*16 + kh*8 + j, tap = k >> 8, c = k & 255;
    int ky = tap / 3, kx = tap - ky*3;
    u16 v = 0;
    if (n < 27) v = f2b(w_off[((n*256 + c)*3 + ky)*3 + kx]);
    Boff[i] = v;
  }
  if (i < 144*4*2*32*8){
    int j = i & 7, n = (i >> 3) & 31, kh = (i >> 8) & 1, a4 = (i >> 9) & 3, kc = i >> 11;
    int k = kc*16 + kh*8 + j, tap = k >> 8, c = k & 255;
    int ky = tap / 3, kx = tap - ky*3;
    int o = a4*32 + n;
    Bdcn[i] = f2b(w_dcn[((o*256 + c)*3 + ky)*3 + kx]);
  }
  if (i < 4*32*4*2*32*8){
    int j = i & 7, n = (i >> 3) & 31, kh = (i >> 8) & 1, a4 = (i >> 9) & 3;
    int kc = (i >> 11) & 31, pp = i >> 16;
    int k = kc*16 + kh*8 + j, tapd = k >> 7, c = k & 127;
    int o = a4*32 + n;
    int py = pp >> 1, px = pp & 1, dy = tapd >> 1, dx = tapd & 1;
    Bup[i] = f2b(w_up[((c*128 + o)*4 + (3-(py+2*dy)))*4 + (3-(px+2*dx))]);
  }
}

// ---------------- x NCHW f32 -> NHWC bf16 ----------------
__global__ __launch_bounds__(256) void transpose_kernel(const float* __restrict__ x, u16* __restrict__ xt){
  __shared__ u16 Ls[64][65];
  int blk = blockIdx.x;                 // 1024 = 4b * 64h * 4cb
  int cb = blk & 3, h = (blk >> 2) & 63, b = blk >> 8;
  int t = threadIdx.x;
  int c0 = cb * 64;
  for (int i = 0; i < 16; i++){
    int idx = t + i*256;
    int c = idx >> 6, w = idx & 63;
    Ls[c][w] = f2b(x[((b*256 + c0 + c)*64 + h)*64 + w]);
  }
  __syncthreads();
  for (int i = 0; i < 16; i++){
    int idx = t + i*256;
    int w = idx >> 6, cc = idx & 63;
    xt[(((b*64 + h)*64 + w) << 8) + c0 + cc] = Ls[cc][w];
  }
}

// ---------------- stage 1: offset conv; LDS row-staged A, fragment B, 4-wave K-split ----------------
__global__ __launch_bounds__(256) void convoff_kernel(const u16* __restrict__ xt,
                                                      const u16* __restrict__ Boff,
                                                      const float* __restrict__ b_off,
                                                      float* __restrict__ om){
  __shared__ alignas(16) u16 As[32*264];   // [px 32][ch 256 + 8 pad]
  __shared__ float Ys[3][64][17];
  int blk = blockIdx.x;                 // 512 = 4b * 64h * 2wt
  int wt = blk & 1, h = (blk >> 1) & 63, b = blk >> 7;
  int w0 = wt * 32;
  int t = threadIdx.x;
  int wv = t >> 6, lane = t & 63;
  int m = lane & 31, kh = lane >> 5;
  f32x16 acc = {0.f};

  for (int tap = 0; tap < 9; tap++){
    int ky = tap / 3, kx = tap - ky*3;
    int y = h + ky - 1;
    bool rowok = (u32)y < 64u;
    // stage 32px x 256ch (coalesced 512B-per-pixel segments)
    #pragma unroll
    for (int it = 0; it < 4; it++){
      int idx = it*256 + t;
      int px = idx >> 5, c16 = idx & 31;
      int xw = w0 + px + kx - 1;
      uint4 v = make_uint4(0,0,0,0);
      if (rowok && (u32)xw < 64u)
        v = *(const uint4*)(xt + (((b*64 + y)*64 + xw) << 8) + c16*8);
      *(uint4*)(As + px*264 + c16*8) = v;
    }
    __syncthreads();
    #pragma unroll
    for (int q = 0; q < 4; q++){
      int kcl = wv*4 + q;
      int kcg = tap*16 + kcl;
      short8 a  = *(const short8*)(As + m*264 + kcl*16 + kh*8);
      short8 bb = *(const short8*)(Boff + ((kcg*2 + kh)*32 + m)*8);
      acc = mfma32(a, bb, acc);
    }
    __syncthreads();
  }
  if (wv > 0){
    #pragma unroll
    for (int r = 0; r < 16; r++) Ys[wv-1][lane][r] = acc[r];
  }
  __syncthreads();
  if (wv == 0){
    int n = m;
    float bias = (n < 27) ? b_off[n] : 0.f;
    #pragma unroll
    for (int r = 0; r < 16; r++){
      float s = acc[r] + Ys[0][lane][r] + Ys[1][lane][r] + Ys[2][lane][r];
      int row = (r & 3) + 8*(r >> 2) + 4*kh;
      int pix = (b*64 + h)*64 + w0 + row;
      if (n < 27) om[pix*32 + n] = s + bias;
    }
  }
}

// ---------------- stage 2: mdcn; coalesced per-pixel gather -> LDS slab -> MFMA ----------------
__global__ __launch_bounds__(256) void mdcn_kernel(const u16* __restrict__ xt,
                                                   const float* __restrict__ om,
                                                   const u16* __restrict__ Bdcn,
                                                   const float* __restrict__ b_dcn,
                                                   u16* __restrict__ yb){
  __shared__ alignas(16) char smem[49920];          // union: As (16896 B) | Ys (49920 B)
  u16* As = (u16*)smem;                             // [px 32][ch 256 + 8 pad]
  float (*Ys)[64][65] = (float (*)[64][65])smem;    // [3][64][65]
  int blk = blockIdx.x;                 // 512 = 4b * 64h * 2wt
  int wt = blk & 1, h = (blk >> 1) & 63, b = blk >> 7;
  int w0 = wt * 32;
  int P0 = (b*64 + h)*64 + w0;
  int t = threadIdx.x;
  int wv = t >> 6, lane = t & 63;
  int m = lane & 31, kh = lane >> 5;    // kh doubles as x-column half in staging
  f32x16 acc[4];
  #pragma unroll
  for (int a4 = 0; a4 < 4; a4++) acc[a4] = (f32x16){0.f};

  for (int tap = 0; tap < 9; tap++){
    int ky = tap / 3, kx = tap - ky*3;
    // ---- stage: each wave gathers+blends 8 pixels (coalesced row loads) ----
    #pragma unroll
    for (int e = 0; e < 8; e++){
      int p = wv*8 + e;
      int pix = P0 + p;
      const float* omp = om + pix*32;
      float dy = omp[2*tap], dx = omp[2*tap+1];
      float mk = 1.f / (1.f + __expf(-omp[18+tap]));
      float ys = (float)(h - 1 + ky) + dy;
      float xs = (float)(w0 + p - 1 + kx) + dx;
      float y0f = floorf(ys), x0f = floorf(xs);
      float ly = ys - y0f, lx = xs - x0f;
      int y0 = (int)y0f, x0 = (int)x0f;
      int xx = x0 + kh;                 // lanes 0-31: x0 column; lanes 32-63: x0+1
      bool vx = (u32)xx < 64u;
      bool v0 = vx && ((u32)y0 < 64u);
      bool v1 = vx && ((u32)(y0+1) < 64u);
      float cwt = kh ? lx : (1.f - lx);
      float wtop = (1.f - ly) * cwt * mk;
      float wbot = ly * cwt * mk;
      const u16* base = xt + (((b*64 + y0)*64 + xx) << 8) + m*8;
      uint4 z = make_uint4(0,0,0,0);
      uint4 u0 = v0 ? *(const uint4*)(base) : z;
      uint4 u1 = v1 ? *(const uint4*)(base + (64 << 8)) : z;
      float f0[8], f1[8], s[8];
      unpk(u0, f0); unpk(u1, f1);
      #pragma unroll
      for (int j = 0; j < 8; j++) s[j] = wtop*f0[j] + wbot*f1[j];
      #pragma unroll
      for (int j = 0; j < 8; j++) s[j] += __shfl_xor(s[j], 32);
      if (kh == 0){
        uint4 pv = pk8(s);
        *(uint4*)(As + p*264 + m*8) = pv;
      }
    }
    __syncthreads();
    // ---- compute: K-split across waves (wave wv owns kc-quarter of this tap) ----
    #pragma unroll
    for (int q = 0; q < 4; q++){
      int kcl = wv*4 + q;
      int kcg = tap*16 + kcl;
      short8 a = *(const short8*)(As + m*264 + kcl*16 + kh*8);
      #pragma unroll
      for (int a4 = 0; a4 < 4; a4++){
        short8 bb = *(const short8*)(Bdcn + (((kcg*4 + a4)*2 + kh)*32 + m)*8);
        acc[a4] = mfma32(a, bb, acc[a4]);
      }
    }
    __syncthreads();
  }
  // ---- cross-wave partial reduction (Ys overlays As; barrier above protects) ----
  if (wv > 0){
    #pragma unroll
    for (int a4 = 0; a4 < 4; a4++)
      #pragma unroll
      for (int r = 0; r < 16; r++)
        Ys[wv-1][lane][a4*16 + r] = acc[a4][r];
  }
  __syncthreads();
  if (wv == 0){
    #pragma unroll
    for (int a4 = 0; a4 < 4; a4++){
      int ch = a4*32 + m;
      float bias = b_dcn[ch];
      #pragma unroll
      for (int r = 0; r < 16; r++){
        int i = a4*16 + r;
        float s = acc[a4][r] + Ys[0][lane][i] + Ys[1][lane][i] + Ys[2][lane][i];
        int row = (r & 3) + 8*(r >> 2) + 4*kh;
        yb[(P0 + row)*128 + ch] = f2b(s + bias);
      }
    }
  }
}

// ---------------- BN stats: per-channel sum/sumsq over NHWC bf16 ----------------
__global__ __launch_bounds__(256) void bnstats_kernel(const u16* __restrict__ src,
                                                      float* __restrict__ st, int npix){
  __shared__ float red[256];
  int t = threadIdx.x;
  int ch = t & 127, half = t >> 7;
  float s = 0.f, ss = 0.f;
  for (int p = blockIdx.x*2 + half; p < npix; p += gridDim.x*2){
    float v = b2f(src[p*128 + ch]);
    s += v; ss += v*v;
  }
  red[t] = s; __syncthreads();
  if (t < 128) atomicAdd(&st[t], red[t] + red[t+128]);
  __syncthreads();
  red[t] = ss; __syncthreads();
  if (t < 128) atomicAdd(&st[128 + t], red[t] + red[t+128]);
}

// ---------------- BN finalize ----------------
__global__ __launch_bounds__(128) void bnfin_kernel(const float* __restrict__ stats,
                                                    const float* __restrict__ gamma,
                                                    const float* __restrict__ beta,
                                                    float2* __restrict__ bn,
                                                    float invN){
  int o = threadIdx.x;
  float mean = stats[o] * invN;
  float var  = stats[128 + o] * invN - mean*mean;
  float inv  = rsqrtf(var + 1e-5f);
  float sc   = gamma[o] * inv;
  bn[o] = make_float2(sc, beta[o] - mean * sc);
}

// ---------------- stage 4: deconv; LDS row window (bn1+relu fused at stage), fragment B ----------------
__global__ __launch_bounds__(256) void deconv_kernel(const u16* __restrict__ yb,
                                                     const float2* __restrict__ bn1,
                                                     const u16* __restrict__ Bup,
                                                     u16* __restrict__ y2){
  __shared__ alignas(16) u16 Ls[2*66*136];   // [r 2][ww1 66][128 ch + 8 pad]
  int blk = blockIdx.x;                 // 512 = 4b * 128yy
  int yy = blk & 127, b = blk >> 7;
  int pary = yy & 1;
  int hs = (yy - 2 + pary) >> 1;        // may be -1 or 64-OOB row handled below
  int t = threadIdx.x;
  // this thread's channel group (constant across stage iters): c16 = t&15
  float2 bnv[8];
  {
    const float2* bp = bn1 + (t & 15)*8;
    #pragma unroll
    for (int e = 0; e < 8; e++) bnv[e] = bp[e];
  }
  #pragma unroll
  for (int it = 0; it < 8; it++){
    int idx = it*256 + t;
    int r = idx >> 10, rem = idx & 1023, px = rem >> 4, c16 = rem & 15;
    int hh = hs + r;
    uint4 u = make_uint4(0,0,0,0);
    if ((u32)hh < 64u)
      u = *(const uint4*)(yb + (((b*64 + hh)*64 + px) << 7) + c16*8);
    float f[8]; unpk(u, f);
    float o[8];
    #pragma unroll
    for (int e = 0; e < 8; e++) o[e] = fmaxf(0.f, fmaf(bnv[e].x, f[e], bnv[e].y));
    uint4 w = pk8(o);
    *(uint4*)(Ls + (r*66 + px + 1)*136 + c16*8) = w;
  }
  if (t < 64){
    int r = t >> 5, we = (t >> 4) & 1, c16 = t & 15;
    *(uint4*)(Ls + (r*66 + we*65)*136 + c16*8) = make_uint4(0,0,0,0);
  }
  __syncthreads();

  int wv = t >> 6, lane = t & 63;
  int m = lane & 31, kh = lane >> 5;
  int parx = wv & 1, xtl = wv >> 1;
  int pp = pary*2 + parx;
  f32x16 acc[4];
  #pragma unroll
  for (int a4 = 0; a4 < 4; a4++) acc[a4] = (f32x16){0.f};

  #pragma unroll
  for (int tapd = 0; tapd < 4; tapd++){
    int dyy = tapd >> 1, dxx = tapd & 1;
    int ww1 = xtl*32 + parx + dxx + m;  // in [0,65]
    const u16* lp = Ls + (dyy*66 + ww1)*136;
    #pragma unroll
    for (int q = 0; q < 8; q++){
      short8 a = *(const short8*)(lp + q*16 + kh*8);
      #pragma unroll
      for (int a4 = 0; a4 < 4; a4++){
        short8 bb = *(const short8*)(Bup + ((((pp*32 + tapd*8 + q)*4 + a4)*2 + kh)*32 + m)*8);
        acc[a4] = mfma32(a, bb, acc[a4]);
      }
    }
  }
  #pragma unroll
  for (int a4 = 0; a4 < 4; a4++){
    int ch = a4*32 + m;
    #pragma unroll
    for (int r = 0; r < 16; r++){
      int row = (r & 3) + 8*(r >> 2) + 4*kh;
      int jj = xtl*32 + row;
      int xx = parx + 2*jj;
      y2[(((b*128 + yy)*128 + xx) << 7) + ch] = f2b(acc[a4][r]);
    }
  }
}

// ---------------- stage 5: BN2 + ReLU + NHWC->NCHW, f32 out ----------------
__global__ __launch_bounds__(256) void final_kernel(const u16* __restrict__ y2,
                                                    const float2* __restrict__ bn2,
                                                    float* __restrict__ outp){
  __shared__ u16 Ls[128*132];
  __shared__ float2 BNs[128];
  int blk = blockIdx.x;                 // 512 = 4b * 128y
  int yy = blk & 127, b = blk >> 7;
  int t = threadIdx.x;
  if (t < 128) BNs[t] = bn2[t];
  __syncthreads();
  for (int i = 0; i < 8; i++){
    int x = i*16 + (t >> 4);
    int og = (t & 15) * 8;
    uint4 u = *(const uint4*)(y2 + (((b*128 + yy)*128 + x) << 7) + og);
    float f[8]; unpk(u, f);
    for (int e = 0; e < 8; e++){
      float2 sc = BNs[og + e];
      Ls[(og + e)*132 + x] = f2b(fmaxf(0.f, fmaf(sc.x, f[e], sc.y)));
    }
  }
  __syncthreads();
  for (int i = 0; i < 16; i++){
    int idx = i*256 + t;
    int o = idx >> 5, xg = (idx & 31) * 4;
    float4 v;
    v.x = b2f(Ls[o*132 + xg + 0]);
    v.y = b2f(Ls[o*132 + xg + 1]);
    v.z = b2f(Ls[o*132 + xg + 2]);
    v.w = b2f(Ls[o*132 + xg + 3]);
    *(float4*)(outp + (((b*128 + o)*128 + yy) << 7) + xg) = v;
  }
}

extern "C" void kernel_launch(void* const* d_in, const int* in_sizes, int n_in,
                              void* d_out, int out_size, void* d_ws, size_t ws_size,
                              hipStream_t stream) {
  const float* x      = (const float*)d_in[0];
  const float* w_off  = (const float*)d_in[1];
  const float* b_off  = (const float*)d_in[2];
  const float* w_dcn  = (const float*)d_in[3];
  const float* b_dcn  = (const float*)d_in[4];
  const float* gamma1 = (const float*)d_in[5];
  const float* beta1  = (const float*)d_in[6];
  const float* w_up   = (const float*)d_in[7];
  const float* gamma2 = (const float*)d_in[8];
  const float* beta2  = (const float*)d_in[9];

  char* ws = (char*)d_ws;
  u16*   xt    = (u16*)(ws + OFF_XT);
  float* om    = (float*)(ws + OFF_OM);
  u16*   yb    = (u16*)(ws + OFF_Y);
  u16*   y2    = (u16*)(ws + OFF_Y2);
  u16*   Boff  = (u16*)(ws + OFF_BOFF);
  u16*   Bdcn  = (u16*)(ws + OFF_BDCN);
  u16*   Bup   = (u16*)(ws + OFF_BUP);
  float* stats = (float*)(ws + OFF_STATS);
  float2* bn1  = (float2*)(ws + OFF_BN1);
  float2* bn2  = (float2*)(ws + OFF_BN2);

  hipMemsetAsync(stats, 0, 2048, stream);
  prep_kernel<<<1152, 256, 0, stream>>>(w_off, w_dcn, w_up, Boff, Bdcn, Bup);
  transpose_kernel<<<1024, 256, 0, stream>>>(x, xt);
  convoff_kernel<<<512, 256, 0, stream>>>(xt, Boff, b_off, om);
  mdcn_kernel<<<512, 256, 0, stream>>>(xt, om, Bdcn, b_dcn, yb);
  bnstats_kernel<<<256, 256, 0, stream>>>(yb, stats, 16384);
  bnfin_kernel<<<1, 128, 0, stream>>>(stats, gamma1, beta1, bn1, 1.f/16384.f);
  deconv_kernel<<<512, 256, 0, stream>>>(yb, bn1, Bup, y2);
  bnstats_kernel<<<512, 256, 0, stream>>>(y2, stats + 256, 65536);
  bnfin_kernel<<<1, 128, 0, stream>>>(stats + 256, gamma2, beta2, bn2, 1.f/65536.f);
  final_kernel<<<512, 256, 0, stream>>>(y2, bn2, (float*)d_out);
}

// Round 7
// 286.704 us; speedup vs baseline: 1.4144x; 1.0473x over previous
//
#include <hip/hip_runtime.h>
#include <hip/hip_bf16.h>

typedef __attribute__((ext_vector_type(8))) short short8;
typedef __attribute__((ext_vector_type(4))) float f32x4;
typedef __attribute__((ext_vector_type(16))) float f32x16;
typedef unsigned short u16;
typedef unsigned int u32;

// ---------------- workspace layout (bytes) ----------------
#define OFF_XT      0u          // x NHWC bf16: 4*64*64*256 = 8388608 B
#define OFF_OM      8388608u    // offsets fp32: 16384*32*4  = 2097152 B
#define OFF_Y       10485760u   // mdcn out NHWC bf16: 16384*128*2 = 4194304 B
#define OFF_Y2      14680064u   // deconv out NHWC bf16: 65536*128*2 = 16777216 B
#define OFF_BOFF    31457280u   // Boff16 [72][2][64][8] bf16 = 147456 B
#define OFF_BDCN    31604736u   // Bdcn16 [72][8][64][8] bf16 = 589824 B
#define OFF_BUP     32194560u   // Bup'  [4][32][4][2][32][8] bf16 = 524288 B
#define OFF_STATS   32718848u   // stats1 sum/ss [256] + stats2 [256] f32 = 2048 B
#define OFF_BN1     32720896u   // float2[128]
#define OFF_BN2     32721920u   // float2[128]

__device__ __forceinline__ float lo2f(u32 u){ u32 v = u << 16; float f; __builtin_memcpy(&f, &v, 4); return f; }
__device__ __forceinline__ float hi2f(u32 u){ u32 v = u & 0xffff0000u; float f; __builtin_memcpy(&f, &v, 4); return f; }
__device__ __forceinline__ float b2f(u16 v){ u32 u = ((u32)v) << 16; float f; __builtin_memcpy(&f, &u, 4); return f; }
__device__ __forceinline__ u16 f2b(float f){ __hip_bfloat16 h = __float2bfloat16(f); u16 r; __builtin_memcpy(&r, &h, 2); return r; }
// fast RNE f32->bf16 (finite values only)
__device__ __forceinline__ u32 rne(float f){ u32 u; __builtin_memcpy(&u, &f, 4); return u + 0x7FFFu + ((u >> 16) & 1u); }
__device__ __forceinline__ u32 pk2(float f0, float f1){ return (rne(f0) >> 16) | (rne(f1) & 0xFFFF0000u); }

__device__ __forceinline__ f32x4 mfma16(short8 a, short8 b, f32x4 c){
  return __builtin_amdgcn_mfma_f32_16x16x32_bf16(a, b, c, 0, 0, 0);
}
__device__ __forceinline__ f32x16 mfma32(short8 a, short8 b, f32x16 c){
  return __builtin_amdgcn_mfma_f32_32x32x16_bf16(a, b, c, 0, 0, 0);
}
__device__ __forceinline__ void unpk(uint4 u, float* f){
  f[0]=lo2f(u.x); f[1]=hi2f(u.x); f[2]=lo2f(u.y); f[3]=hi2f(u.y);
  f[4]=lo2f(u.z); f[5]=hi2f(u.z); f[6]=lo2f(u.w); f[7]=hi2f(u.w);
}
__device__ __forceinline__ uint4 pk8(const float* f){
  uint4 r;
  r.x = pk2(f[0], f[1]); r.y = pk2(f[2], f[3]);
  r.z = pk2(f[4], f[5]); r.w = pk2(f[6], f[7]);
  return r;
}

// ---------------- weight reorg into MFMA-fragment layouts (f32 -> bf16) ----------------
// Boff16[kc 72][nt 2][lane 64][j 8] : n=nt*16+(lane&15), k=kc*32+((lane>>4)&3)*8+j, tap=k>>8, c=k&255
// Bdcn16[kc 72][nt 8][lane 64][j 8] : o=nt*16+(lane&15), same k decode
// Bup'  [pp 4][kc 32][a4 4][kh 2][n 32][j 8] (32x32 frag, K=512): k=kc*16+kh*8+j, tapd=k>>7, c=k&127
__global__ __launch_bounds__(256) void prep_kernel(const float* __restrict__ w_off,
                                                   const float* __restrict__ w_dcn,
                                                   const float* __restrict__ w_up,
                                                   u16* __restrict__ Boff,
                                                   u16* __restrict__ Bdcn,
                                                   u16* __restrict__ Bup){
  int i = blockIdx.x * 256 + threadIdx.x;
  if (i < 72*2*64*8){
    int j = i & 7, lane = (i >> 3) & 63, nt = (i >> 9) & 1, kc = i >> 10;
    int n = nt*16 + (lane & 15);
    int k = kc*32 + ((lane >> 4) & 3)*8 + j, tap = k >> 8, c = k & 255;
    int ky = tap / 3, kx = tap - ky*3;
    u16 v = 0;
    if (n < 27) v = f2b(w_off[((n*256 + c)*3 + ky)*3 + kx]);
    Boff[i] = v;
  }
  if (i < 72*8*64*8){
    int j = i & 7, lane = (i >> 3) & 63, nt = (i >> 9) & 7, kc = i >> 12;
    int o = nt*16 + (lane & 15);
    int k = kc*32 + ((lane >> 4) & 3)*8 + j, tap = k >> 8, c = k & 255;
    int ky = tap / 3, kx = tap - ky*3;
    Bdcn[i] = f2b(w_dcn[((o*256 + c)*3 + ky)*3 + kx]);
  }
  if (i < 4*32*4*2*32*8){
    int j = i & 7, n = (i >> 3) & 31, kh = (i >> 8) & 1, a4 = (i >> 9) & 3;
    int kc = (i >> 11) & 31, pp = i >> 16;
    int k = kc*16 + kh*8 + j, tapd = k >> 7, c = k & 127;
    int o = a4*32 + n;
    int py = pp >> 1, px = pp & 1, dy = tapd >> 1, dx = tapd & 1;
    Bup[i] = f2b(w_up[((c*128 + o)*4 + (3-(py+2*dy)))*4 + (3-(px+2*dx))]);
  }
}

// ---------------- x NCHW f32 -> NHWC bf16 ----------------
__global__ __launch_bounds__(256) void transpose_kernel(const float* __restrict__ x, u16* __restrict__ xt){
  __shared__ u16 Ls[64][65];
  int blk = blockIdx.x;                 // 1024 = 4b * 64h * 4cb
  int cb = blk & 3, h = (blk >> 2) & 63, b = blk >> 8;
  int t = threadIdx.x;
  int c0 = cb * 64;
  for (int i = 0; i < 16; i++){
    int idx = t + i*256;
    int c = idx >> 6, w = idx & 63;
    Ls[c][w] = f2b(x[((b*256 + c0 + c)*64 + h)*64 + w]);
  }
  __syncthreads();
  for (int i = 0; i < 16; i++){
    int idx = t + i*256;
    int w = idx >> 6, cc = idx & 63;
    xt[(((b*64 + h)*64 + w) << 8) + c0 + cc] = Ls[cc][w];
  }
}

// ---------------- stage 1: offset conv; 16-px blocks, mfma16, 4-wave K-split ----------------
__global__ __launch_bounds__(256, 4) void convoff_kernel(const u16* __restrict__ xt,
                                                         const u16* __restrict__ Boff,
                                                         const float* __restrict__ b_off,
                                                         float* __restrict__ om){
  __shared__ alignas(16) u16 As[16*264];      // [px 16][ch 256 + 8 pad]
  __shared__ float Ys[4*16*36];               // [wv 4][px 16][n 32 + 4 pad]
  int blk = blockIdx.x;                 // 1024 = 4b * 64h * 4wt
  int wt = blk & 3, h = (blk >> 2) & 63, b = blk >> 8;
  int w0 = wt * 16;
  int P0 = (b*64 + h)*64 + w0;
  int t = threadIdx.x;
  int wv = t >> 6, lane = t & 63;
  int ln = lane & 15, q4 = (lane >> 4) & 3;
  f32x4 acc[2];
  acc[0] = (f32x4){0.f,0.f,0.f,0.f};
  acc[1] = (f32x4){0.f,0.f,0.f,0.f};

  for (int tap = 0; tap < 9; tap++){
    int ky = tap / 3, kx = tap - ky*3;
    int y = h + ky - 1;
    bool rowok = (u32)y < 64u;
    #pragma unroll
    for (int it = 0; it < 2; it++){
      int idx = it*256 + t;
      int px = idx >> 5, c16 = idx & 31;
      int xw = w0 + px + kx - 1;
      uint4 v = make_uint4(0,0,0,0);
      if (rowok && (u32)xw < 64u)
        v = *(const uint4*)(xt + (((b*64 + y)*64 + xw) << 8) + c16*8);
      *(uint4*)(As + px*264 + c16*8) = v;
    }
    __syncthreads();
    #pragma unroll
    for (int q = 0; q < 2; q++){
      int kof = wv*64 + q*32;
      int kcg = tap*8 + wv*2 + q;
      short8 a = *(const short8*)(As + ln*264 + kof + q4*8);
      #pragma unroll
      for (int nt = 0; nt < 2; nt++){
        short8 bb = *(const short8*)(Boff + ((kcg*2 + nt)*64 + lane)*8);
        acc[nt] = mfma16(a, bb, acc[nt]);
      }
    }
    __syncthreads();
  }
  #pragma unroll
  for (int nt = 0; nt < 2; nt++)
    #pragma unroll
    for (int r = 0; r < 4; r++)
      Ys[(wv*16 + q4*4 + r)*36 + nt*16 + ln] = acc[nt][r];
  __syncthreads();
  {
    int px = t >> 4, s = t & 15;
    #pragma unroll
    for (int half = 0; half < 2; half++){
      int n = s + half*16;
      if (n < 27){
        float sum = Ys[(px)*36 + n] + Ys[(16 + px)*36 + n]
                  + Ys[(32 + px)*36 + n] + Ys[(48 + px)*36 + n] + b_off[n];
        om[(P0 + px)*32 + n] = sum;
      }
    }
  }
}

// ---------------- stage 2: mdcn; 16-px blocks, om in LDS, mfma16, 4-wave K-split ----------------
__global__ __launch_bounds__(256, 4) void mdcn_kernel(const u16* __restrict__ xt,
                                                      const float* __restrict__ om,
                                                      const u16* __restrict__ Bdcn,
                                                      const float* __restrict__ b_dcn,
                                                      u16* __restrict__ yb){
  __shared__ alignas(16) char smem[33792];    // union: As(8448)+omL(2048) | Ys(33792)
  u16* As = (u16*)smem;                       // [px 16][ch 256 + 8 pad]
  float* omL = (float*)(smem + 8448);         // [px 16][32]
  float* Ys = (float*)smem;                   // [wv 4][px 16][ch 128 + 4 pad]
  int blk = blockIdx.x;                 // 1024 = 4b * 64h * 4wt
  int wt = blk & 3, h = (blk >> 2) & 63, b = blk >> 8;
  int w0 = wt * 16;
  int P0 = (b*64 + h)*64 + w0;
  int t = threadIdx.x;
  int wv = t >> 6, lane = t & 63;
  int m = lane & 31, kh = lane >> 5;
  int ln = lane & 15, q4 = (lane >> 4) & 3;
  omL[t]       = om[P0*32 + t];
  omL[256 + t] = om[P0*32 + 256 + t];
  __syncthreads();
  f32x4 acc[8];
  #pragma unroll
  for (int nt = 0; nt < 8; nt++) acc[nt] = (f32x4){0.f,0.f,0.f,0.f};

  for (int tap = 0; tap < 9; tap++){
    int ky = tap / 3, kx = tap - ky*3;
    // ---- stage: each wave blends 4 pixels; coalesced 512B row segments ----
    #pragma unroll
    for (int e = 0; e < 4; e++){
      int p = wv*4 + e;
      float dy = omL[p*32 + 2*tap];
      float dxv = omL[p*32 + 2*tap + 1];
      float mk = 1.f / (1.f + __expf(-omL[p*32 + 18 + tap]));
      float ys = (float)(h - 1 + ky) + dy;
      float xs = (float)(w0 + p - 1 + kx) + dxv;
      float y0f = floorf(ys), x0f = floorf(xs);
      float ly = ys - y0f, lx = xs - x0f;
      int y0 = (int)y0f, x0 = (int)x0f;
      int xx = x0 + kh;                 // lanes 0-31: col x0; 32-63: col x0+1
      bool vx = (u32)xx < 64u;
      bool v0 = vx && ((u32)y0 < 64u);
      bool v1 = vx && ((u32)(y0+1) < 64u);
      float cwt = kh ? lx : (1.f - lx);
      float wtop = (1.f - ly) * cwt * mk;
      float wbot = ly * cwt * mk;
      const u16* base = xt + (((b*64 + y0)*64 + xx) << 8) + m*8;
      uint4 z = make_uint4(0,0,0,0);
      uint4 u0 = v0 ? *(const uint4*)(base) : z;
      uint4 u1 = v1 ? *(const uint4*)(base + (64 << 8)) : z;
      float f0[8], f1[8], s[8];
      unpk(u0, f0); unpk(u1, f1);
      #pragma unroll
      for (int j = 0; j < 8; j++) s[j] = wtop*f0[j] + wbot*f1[j];
      #pragma unroll
      for (int j = 0; j < 8; j++) s[j] += __shfl_xor(s[j], 32);
      if (kh == 0)
        *(uint4*)(As + p*264 + m*8) = pk8(s);
    }
    __syncthreads();
    // ---- compute: wave owns 64-ch K-slice of this tap ----
    #pragma unroll
    for (int q = 0; q < 2; q++){
      int kof = wv*64 + q*32;
      int kcg = tap*8 + wv*2 + q;
      short8 a = *(const short8*)(As + ln*264 + kof + q4*8);
      #pragma unroll
      for (int nt = 0; nt < 8; nt++){
        short8 bb = *(const short8*)(Bdcn + ((kcg*8 + nt)*64 + lane)*8);
        acc[nt] = mfma16(a, bb, acc[nt]);
      }
    }
    __syncthreads();
  }
  // ---- partials to LDS (Ys overlays As/omL; last loop barrier protects) ----
  #pragma unroll
  for (int nt = 0; nt < 8; nt++)
    #pragma unroll
    for (int r = 0; r < 4; r++)
      Ys[(wv*16 + q4*4 + r)*132 + nt*16 + ln] = acc[nt][r];
  __syncthreads();
  {
    int px = t >> 4, cg = t & 15;
    float f[8];
    #pragma unroll
    for (int e = 0; e < 8; e++){
      int ch = cg*8 + e;
      f[e] = Ys[(px)*132 + ch] + Ys[(16 + px)*132 + ch]
           + Ys[(32 + px)*132 + ch] + Ys[(48 + px)*132 + ch] + b_dcn[ch];
    }
    *(uint4*)(yb + (P0 + px)*128 + cg*8) = pk8(f);
  }
}

// ---------------- BN stats: per-channel sum/sumsq over NHWC bf16 ----------------
__global__ __launch_bounds__(256) void bnstats_kernel(const u16* __restrict__ src,
                                                      float* __restrict__ st, int npix){
  __shared__ float red[256];
  int t = threadIdx.x;
  int ch = t & 127, half = t >> 7;
  float s = 0.f, ss = 0.f;
  for (int p = blockIdx.x*2 + half; p < npix; p += gridDim.x*2){
    float v = b2f(src[p*128 + ch]);
    s += v; ss += v*v;
  }
  red[t] = s; __syncthreads();
  if (t < 128) atomicAdd(&st[t], red[t] + red[t+128]);
  __syncthreads();
  red[t] = ss; __syncthreads();
  if (t < 128) atomicAdd(&st[128 + t], red[t] + red[t+128]);
}

// ---------------- BN finalize ----------------
__global__ __launch_bounds__(128) void bnfin_kernel(const float* __restrict__ stats,
                                                    const float* __restrict__ gamma,
                                                    const float* __restrict__ beta,
                                                    float2* __restrict__ bn,
                                                    float invN){
  int o = threadIdx.x;
  float mean = stats[o] * invN;
  float var  = stats[128 + o] * invN - mean*mean;
  float inv  = rsqrtf(var + 1e-5f);
  float sc   = gamma[o] * inv;
  bn[o] = make_float2(sc, beta[o] - mean * sc);
}

// ---------------- stage 4: deconv; LDS row window, fragment B, LDS-staged coalesced out ----------------
__global__ __launch_bounds__(256) void deconv_kernel(const u16* __restrict__ yb,
                                                     const float2* __restrict__ bn1,
                                                     const u16* __restrict__ Bup,
                                                     u16* __restrict__ y2){
  __shared__ alignas(16) char smem[35904];    // union: Ls [2][66][136] u16 | Lo [128][136] u16
  u16* Ls = (u16*)smem;
  u16* Lo = (u16*)smem;
  int blk = blockIdx.x;                 // 512 = 4b * 128yy
  int yy = blk & 127, b = blk >> 7;
  int pary = yy & 1;
  int hs = (yy - 2 + pary) >> 1;        // may be -1 / OOB, guarded below
  int t = threadIdx.x;
  float2 bnv[8];
  {
    const float2* bp = bn1 + (t & 15)*8;
    #pragma unroll
    for (int e = 0; e < 8; e++) bnv[e] = bp[e];
  }
  #pragma unroll
  for (int it = 0; it < 8; it++){
    int idx = it*256 + t;
    int r = idx >> 10, rem = idx & 1023, px = rem >> 4, c16 = rem & 15;
    int hh = hs + r;
    uint4 u = make_uint4(0,0,0,0);
    if ((u32)hh < 64u)
      u = *(const uint4*)(yb + (((b*64 + hh)*64 + px) << 7) + c16*8);
    float f[8]; unpk(u, f);
    float o[8];
    #pragma unroll
    for (int e = 0; e < 8; e++) o[e] = fmaxf(0.f, fmaf(bnv[e].x, f[e], bnv[e].y));
    *(uint4*)(Ls + (r*66 + px + 1)*136 + c16*8) = pk8(o);
  }
  if (t < 64){
    int r = t >> 5, we = (t >> 4) & 1, c16 = t & 15;
    *(uint4*)(Ls + (r*66 + we*65)*136 + c16*8) = make_uint4(0,0,0,0);
  }
  __syncthreads();

  int wv = t >> 6, lane = t & 63;
  int m = lane & 31, kh = lane >> 5;
  int parx = wv & 1, xtl = wv >> 1;
  int pp = pary*2 + parx;
  f32x16 acc[4];
  #pragma unroll
  for (int a4 = 0; a4 < 4; a4++) acc[a4] = (f32x16){0.f};

  #pragma unroll
  for (int tapd = 0; tapd < 4; tapd++){
    int dyy = tapd >> 1, dxx = tapd & 1;
    int ww1 = xtl*32 + parx + dxx + m;  // in [0,65]
    const u16* lp = Ls + (dyy*66 + ww1)*136;
    #pragma unroll
    for (int q = 0; q < 8; q++){
      short8 a = *(const short8*)(lp + q*16 + kh*8);
      #pragma unroll
      for (int a4 = 0; a4 < 4; a4++){
        short8 bb = *(const short8*)(Bup + ((((pp*32 + tapd*8 + q)*4 + a4)*2 + kh)*32 + m)*8);
        acc[a4] = mfma32(a, bb, acc[a4]);
      }
    }
  }
  __syncthreads();                      // done reading Ls; Lo overlays it
  #pragma unroll
  for (int a4 = 0; a4 < 4; a4++){
    int ch = a4*32 + m;
    #pragma unroll
    for (int r = 0; r < 16; r++){
      int row = (r & 3) + 8*(r >> 2) + 4*kh;
      int jj = xtl*32 + row;
      int xx = parx + 2*jj;
      Lo[xx*136 + ch] = (u16)(rne(acc[a4][r]) >> 16);
    }
  }
  __syncthreads();
  #pragma unroll
  for (int it = 0; it < 8; it++){
    int idx = it*256 + t;
    int xx = idx >> 4, cg = idx & 15;
    uint4 u = *(const uint4*)(Lo + xx*136 + cg*8);
    *(uint4*)(y2 + (((b*128 + yy)*128 + xx) << 7) + cg*8) = u;
  }
}

// ---------------- stage 5: BN2 + ReLU + NHWC->NCHW, f32 out ----------------
__global__ __launch_bounds__(256) void final_kernel(const u16* __restrict__ y2,
                                                    const float2* __restrict__ bn2,
                                                    float* __restrict__ outp){
  __shared__ u16 Ls[128*132];
  __shared__ float2 BNs[128];
  int blk = blockIdx.x;                 // 512 = 4b * 128y
  int yy = blk & 127, b = blk >> 7;
  int t = threadIdx.x;
  if (t < 128) BNs[t] = bn2[t];
  __syncthreads();
  for (int i = 0; i < 8; i++){
    int x = i*16 + (t >> 4);
    int og = (t & 15) * 8;
    uint4 u = *(const uint4*)(y2 + (((b*128 + yy)*128 + x) << 7) + og);
    float f[8]; unpk(u, f);
    for (int e = 0; e < 8; e++){
      float2 sc = BNs[og + e];
      Ls[(og + e)*132 + x] = f2b(fmaxf(0.f, fmaf(sc.x, f[e], sc.y)));
    }
  }
  __syncthreads();
  for (int i = 0; i < 16; i++){
    int idx = i*256 + t;
    int o = idx >> 5, xg = (idx & 31) * 4;
    float4 v;
    v.x = b2f(Ls[o*132 + xg + 0]);
    v.y = b2f(Ls[o*132 + xg + 1]);
    v.z = b2f(Ls[o*132 + xg + 2]);
    v.w = b2f(Ls[o*132 + xg + 3]);
    *(float4*)(outp + (((b*128 + o)*128 + yy) << 7) + xg) = v;
  }
}

extern "C" void kernel_launch(void* const* d_in, const int* in_sizes, int n_in,
                              void* d_out, int out_size, void* d_ws, size_t ws_size,
                              hipStream_t stream) {
  const float* x      = (const float*)d_in[0];
  const float* w_off  = (const float*)d_in[1];
  const float* b_off  = (const float*)d_in[2];
  const float* w_dcn  = (const float*)d_in[3];
  const float* b_dcn  = (const float*)d_in[4];
  const float* gamma1 = (const float*)d_in[5];
  const float* beta1  = (const float*)d_in[6];
  const float* w_up   = (const float*)d_in[7];
  const float* gamma2 = (const float*)d_in[8];
  const float* beta2  = (const float*)d_in[9];

  char* ws = (char*)d_ws;
  u16*   xt    = (u16*)(ws + OFF_XT);
  float* om    = (float*)(ws + OFF_OM);
  u16*   yb    = (u16*)(ws + OFF_Y);
  u16*   y2    = (u16*)(ws + OFF_Y2);
  u16*   Boff  = (u16*)(ws + OFF_BOFF);
  u16*   Bdcn  = (u16*)(ws + OFF_BDCN);
  u16*   Bup   = (u16*)(ws + OFF_BUP);
  float* stats = (float*)(ws + OFF_STATS);
  float2* bn1  = (float2*)(ws + OFF_BN1);
  float2* bn2  = (float2*)(ws + OFF_BN2);

  hipMemsetAsync(stats, 0, 2048, stream);
  prep_kernel<<<1152, 256, 0, stream>>>(w_off, w_dcn, w_up, Boff, Bdcn, Bup);
  transpose_kernel<<<1024, 256, 0, stream>>>(x, xt);
  convoff_kernel<<<1024, 256, 0, stream>>>(xt, Boff, b_off, om);
  mdcn_kernel<<<1024, 256, 0, stream>>>(xt, om, Bdcn, b_dcn, yb);
  bnstats_kernel<<<256, 256, 0, stream>>>(yb, stats, 16384);
  bnfin_kernel<<<1, 128, 0, stream>>>(stats, gamma1, beta1, bn1, 1.f/16384.f);
  deconv_kernel<<<512, 256, 0, stream>>>(yb, bn1, Bup, y2);
  bnstats_kernel<<<512, 256, 0, stream>>>(y2, stats + 256, 65536);
  bnfin_kernel<<<1, 128, 0, stream>>>(stats + 256, gamma2, beta2, bn2, 1.f/65536.f);
  final_kernel<<<512, 256, 0, stream>>>(y2, bn2, (float*)d_out);
}